// Round 3
// baseline (1101.525 us; speedup 1.0000x reference)
//
#include <hip/hip_runtime.h>

#define NS 2048      // series = 256*8
#define T 4096
#define F 9
#define CH 62        // pooled-final rows per chunk -> nw=126 (2 clean strips)
#define NCHUNK 9     // 8*62=496, last chunk nr=17

// LDS: channel-major, time-contiguous, even strides
#define LXP 514      // x:  [9][514]   rows t_local in [0,510)
#define LUP 258      // p1: [16][258]  rows j in [0,254)
#define LWP 130      // p2: [32][130]  rows m in [0,126)
#define SM_X  0                  // 9*514  = 4626 floats
#define SM_P2 0                  // 32*130 = 4160 floats (overlaps X; X dead by then)
#define SM_P1 4640               // 16*258 = 4128 floats
#define SM_TOT (4640 + 16*258)   // 8768 floats = 35072 B -> 4 blocks/CU

__global__ __launch_bounds__(256, 4) void fused_cnn(
    const float* __restrict__ x,
    const float* __restrict__ w1, const float* __restrict__ b1,
    const float* __restrict__ w2, const float* __restrict__ b2,
    const float* __restrict__ w3, const float* __restrict__ b3,
    float* __restrict__ feat)
{
    __shared__ float sm[SM_TOT];
    const int tid  = threadIdx.x;
    const int lane = tid & 63;
    const int wid  = tid >> 6;          // wave id 0..3
    const int chunk = blockIdx.x;
    const int n     = blockIdx.y;
    const int r0 = chunk * CH;
    const int nr = min(CH, 513 - r0);   // 62, or 17 on last chunk
    const int nw = 2*nr + 2;            // p2 rows
    const int nu = 4*nr + 6;            // p1 rows
    const int nx = 8*nr + 14;           // x rows

    // ---- stage A: x window -> LDS transposed [f][t_local], zero-padded ----
    {
        const float* xs = x + (size_t)n * (T*F);
        const int gbase = (8*r0 - 14) * F;   // = t0*9
        const int tot = nx * F;
        for (int i = tid; i < tot; i += 256) {
            int tl = i / 9;
            int f  = i - tl*9;
            int gi = gbase + i;
            float v = (gi >= 0 && gi < T*F) ? xs[gi] : 0.f;
            sm[SM_X + f*LXP + tl] = v;
        }
    }
    __syncthreads();

    // ---- stage B: conv1(9->16,k3,p2)+relu+pool2 -> p1[c][j] ----
    // ci-outer / out-channel-inner: 4-float window in regs, acc[4][2] persistent,
    // weights wave-uniform (SGPR) -> no VGPR spills.
    {
        const int SB = (nu + 63) >> 6;
        for (int strip = 0; strip < SB; ++strip) {
            const int j = strip*64 + lane;          // local pooled-u row
            const int u = 4*r0 - 6 + j;
            const bool uok = (j < nu) && (u >= 0) && (u < 2049);
            float acc0[4], acc1[4];
            #pragma unroll
            for (int ic = 0; ic < 4; ++ic) { acc0[ic] = 0.f; acc1[ic] = 0.f; }
            #pragma unroll
            for (int f = 0; f < 9; ++f) {
                const float* xw = sm + SM_X + f*LXP + 2*j;
                float x0 = xw[0], x1 = xw[1], x2 = xw[2], x3 = xw[3];
                #pragma unroll
                for (int ic = 0; ic < 4; ++ic) {
                    const int cu = __builtin_amdgcn_readfirstlane(wid + 4*ic);
                    const float* wp = w1 + cu*27 + f*3;
                    float w0 = wp[0], w1v = wp[1], w2v = wp[2];
                    acc0[ic] = fmaf(x0, w0,  acc0[ic]);
                    acc1[ic] = fmaf(x1, w0,  acc1[ic]);
                    acc0[ic] = fmaf(x1, w1v, acc0[ic]);
                    acc1[ic] = fmaf(x2, w1v, acc1[ic]);
                    acc0[ic] = fmaf(x2, w2v, acc0[ic]);
                    acc1[ic] = fmaf(x3, w2v, acc1[ic]);
                }
            }
            #pragma unroll
            for (int ic = 0; ic < 4; ++ic) {
                const int cu = __builtin_amdgcn_readfirstlane(wid + 4*ic);
                const float bc = b1[cu];
                float res = uok ? fmaxf(fmaxf(acc0[ic] + bc, acc1[ic] + bc), 0.f) : 0.f;
                if (j < nu) sm[SM_P1 + cu*LUP + j] = res;   // 0 = conv pad for stage C
            }
        }
    }
    __syncthreads();

    // ---- stage C: conv2(16->32,k3,p2)+relu+pool2 -> p2[o][m] (overwrites X) ----
    {
        const int SC = (nw + 63) >> 6;
        for (int strip = 0; strip < SC; ++strip) {
            const int m = strip*64 + lane;          // local pooled-w row
            const int w = 2*r0 - 2 + m;
            const bool wok = (m < nw) && (w >= 0) && (w < 1025);
            float acc0[8], acc1[8];
            #pragma unroll
            for (int io = 0; io < 8; ++io) { acc0[io] = 0.f; acc1[io] = 0.f; }
            #pragma unroll
            for (int ci = 0; ci < 16; ++ci) {
                const float* pw = sm + SM_P1 + ci*LUP + 2*m;
                float p0 = pw[0], p1 = pw[1], p2v = pw[2], p3 = pw[3];
                #pragma unroll
                for (int io = 0; io < 8; ++io) {
                    const int ou = __builtin_amdgcn_readfirstlane(wid + 4*io);
                    const float* wp = w2 + ou*48 + ci*3;
                    float w0 = wp[0], w1v = wp[1], w2v = wp[2];
                    acc0[io] = fmaf(p0,  w0,  acc0[io]);
                    acc1[io] = fmaf(p1,  w0,  acc1[io]);
                    acc0[io] = fmaf(p1,  w1v, acc0[io]);
                    acc1[io] = fmaf(p2v, w1v, acc1[io]);
                    acc0[io] = fmaf(p2v, w2v, acc0[io]);
                    acc1[io] = fmaf(p3,  w2v, acc1[io]);
                }
            }
            #pragma unroll
            for (int io = 0; io < 8; ++io) {
                const int ou = __builtin_amdgcn_readfirstlane(wid + 4*io);
                const float bo = b2[ou];
                float res = wok ? fmaxf(fmaxf(acc0[io] + bo, acc1[io] + bo), 0.f) : 0.f;
                if (m < nw) sm[SM_P2 + ou*LWP + m] = res;   // 0 = conv pad for stage D
            }
        }
    }
    __syncthreads();

    // ---- stage D: conv3(32->16,k3,p2)+relu+pool2 -> sum over r -> feat ----
    {
        const bool rok = (lane < nr);
        float acc0[4], acc1[4];
        #pragma unroll
        for (int io = 0; io < 4; ++io) { acc0[io] = 0.f; acc1[io] = 0.f; }
        #pragma unroll
        for (int ci = 0; ci < 32; ++ci) {
            const float* pw = sm + SM_P2 + ci*LWP + 2*lane;
            float p0 = pw[0], p1 = pw[1], p2v = pw[2], p3 = pw[3];
            #pragma unroll
            for (int io = 0; io < 4; ++io) {
                const int ou = __builtin_amdgcn_readfirstlane(wid + 4*io);
                const float* wp = w3 + ou*96 + ci*3;
                float w0 = wp[0], w1v = wp[1], w2v = wp[2];
                acc0[io] = fmaf(p0,  w0,  acc0[io]);
                acc1[io] = fmaf(p1,  w0,  acc1[io]);
                acc0[io] = fmaf(p1,  w1v, acc0[io]);
                acc1[io] = fmaf(p2v, w1v, acc1[io]);
                acc0[io] = fmaf(p2v, w2v, acc0[io]);
                acc1[io] = fmaf(p3,  w2v, acc1[io]);
            }
        }
        #pragma unroll
        for (int io = 0; io < 4; ++io) {
            const int ou = __builtin_amdgcn_readfirstlane(wid + 4*io);
            const float bo = b3[ou];
            float v = fmaxf(fmaxf(acc0[io] + bo, acc1[io] + bo), 0.f);
            v = rok ? v : 0.f;
            #pragma unroll
            for (int off = 32; off >= 1; off >>= 1)
                v += __shfl_down(v, off, 64);
            if (lane == 0) atomicAdd(&feat[n*16 + ou], v);
        }
    }
}

// feat [2048,16] viewed as [256,128]; out[b][q] = max(feat[b,3q..3q+2]) / 513
__global__ void finalize_kernel(const float* __restrict__ feat, float* __restrict__ out) {
    int i = blockIdx.x * blockDim.x + threadIdx.x;
    if (i < 256*42) {
        int b = i / 42;
        int q = i - b*42;
        const float* f = feat + b*128 + q*3;
        out[i] = fmaxf(fmaxf(f[0], f[1]), f[2]) * (1.0f/513.0f);
    }
}

extern "C" void kernel_launch(void* const* d_in, const int* in_sizes, int n_in,
                              void* d_out, int out_size, void* d_ws, size_t ws_size,
                              hipStream_t stream) {
    const float* x  = (const float*)d_in[0];
    const float* w1 = (const float*)d_in[1];
    const float* b1 = (const float*)d_in[2];
    const float* w2 = (const float*)d_in[3];
    const float* b2 = (const float*)d_in[4];
    const float* w3 = (const float*)d_in[5];
    const float* b3 = (const float*)d_in[6];
    float* feat = (float*)d_ws;                       // 2048*16 floats = 128 KB
    hipMemsetAsync(feat, 0, NS*16*sizeof(float), stream);
    dim3 grid(NCHUNK, NS);
    fused_cnn<<<grid, 256, 0, stream>>>(x, w1, b1, w2, b2, w3, b3, feat);
    finalize_kernel<<<(256*42 + 255)/256, 256, 0, stream>>>(feat, (float*)d_out);
}

// Round 4
// 882.390 us; speedup vs baseline: 1.2483x; 1.2483x over previous
//
#include <hip/hip_runtime.h>

#define NS 2048      // series = 256*8
#define T 4096
#define F 9
#define CH 62        // pooled-final rows per chunk -> nw=126 (2 clean strips)
#define NCHUNK 9     // 8*62=496, last chunk nr=17

// LDS: channel-major, time-contiguous, even strides
#define LXP 514      // x:  [9][514]   rows t_local in [0,510)
#define LUP 258      // p1: [16][258]  rows j in [0,254)
#define LWP 130      // p2: [32][130]  rows m in [0,126)
#define SM_X  0                  // 9*514  = 4626 floats
#define SM_P2 0                  // 32*130 = 4160 floats (overlaps X; X dead by then)
#define SM_P1 4640               // 16*258 = 4128 floats
#define SM_TOT (4640 + 16*258)   // 8768 floats = 35072 B -> 4 blocks/CU

// Weight s_loads are chunked behind `#pragma unroll 1` runtime loops whose loop
// var feeds the load ADDRESS: LICM cannot hoist them, scheduler cannot batch
// more than ~48 scalars -> no SGPR/VGPR spill (round-3's 376 MB scratch traffic).
__global__ __launch_bounds__(256) __attribute__((amdgpu_waves_per_eu(4, 4)))
void fused_cnn(
    const float* __restrict__ x,
    const float* __restrict__ w1, const float* __restrict__ b1,
    const float* __restrict__ w2, const float* __restrict__ b2,
    const float* __restrict__ w3, const float* __restrict__ b3,
    float* __restrict__ feat)
{
    __shared__ float sm[SM_TOT];
    const int tid  = threadIdx.x;
    const int lane = tid & 63;
    const int wid  = tid >> 6;          // wave id 0..3
    const int chunk = blockIdx.x;
    const int n     = blockIdx.y;
    const int r0 = chunk * CH;
    const int nr = min(CH, 513 - r0);   // 62, or 17 on last chunk
    const int nw = 2*nr + 2;            // p2 rows
    const int nu = 4*nr + 6;            // p1 rows
    const int nx = 8*nr + 14;           // x rows

    // ---- stage A: x window -> LDS transposed [f][t_local], zero-padded ----
    {
        const float* xs = x + (size_t)n * (T*F);
        const int gbase = (8*r0 - 14) * F;   // = t0*9
        const int tot = nx * F;
        for (int i = tid; i < tot; i += 256) {
            int tl = i / 9;
            int f  = i - tl*9;
            int gi = gbase + i;
            float v = (gi >= 0 && gi < T*F) ? xs[gi] : 0.f;
            sm[SM_X + f*LXP + tl] = v;
        }
    }
    __syncthreads();

    // ---- stage B: conv1(9->16,k3,p2)+relu+pool2 -> p1[c][j] ----
    {
        const int SB = (nu + 63) >> 6;
        #pragma unroll 1
        for (int strip = 0; strip < SB; ++strip) {
            const int j = strip*64 + lane;          // local pooled-u row
            const int u = 4*r0 - 6 + j;
            const bool uok = (j < nu) && (u >= 0) && (u < 2049);
            float acc0[4], acc1[4];
            #pragma unroll
            for (int ic = 0; ic < 4; ++ic) { acc0[ic] = 0.f; acc1[ic] = 0.f; }
            #pragma unroll 1
            for (int fb = 0; fb < 3; ++fb) {        // runtime: weight addr depends on fb
                #pragma unroll
                for (int fi = 0; fi < 3; ++fi) {
                    const int f_ = fb*3 + fi;
                    const float* xw = sm + SM_X + f_*LXP + 2*j;
                    float x0 = xw[0], x1 = xw[1], x2 = xw[2], x3 = xw[3];
                    #pragma unroll
                    for (int ic = 0; ic < 4; ++ic) {
                        const int cu = __builtin_amdgcn_readfirstlane(wid + 4*ic);
                        const float* wp = w1 + cu*27 + fb*9 + fi*3;
                        float wv0 = wp[0], wv1 = wp[1], wv2 = wp[2];
                        acc0[ic] = fmaf(x0, wv0, acc0[ic]);
                        acc1[ic] = fmaf(x1, wv0, acc1[ic]);
                        acc0[ic] = fmaf(x1, wv1, acc0[ic]);
                        acc1[ic] = fmaf(x2, wv1, acc1[ic]);
                        acc0[ic] = fmaf(x2, wv2, acc0[ic]);
                        acc1[ic] = fmaf(x3, wv2, acc1[ic]);
                    }
                }
            }
            #pragma unroll
            for (int ic = 0; ic < 4; ++ic) {
                const int cu = __builtin_amdgcn_readfirstlane(wid + 4*ic);
                const float bc = b1[cu];
                float res = uok ? fmaxf(fmaxf(acc0[ic] + bc, acc1[ic] + bc), 0.f) : 0.f;
                if (j < nu) sm[SM_P1 + cu*LUP + j] = res;   // 0 = conv pad for stage C
            }
        }
    }
    __syncthreads();

    // ---- stage C: conv2(16->32,k3,p2)+relu+pool2 -> p2[o][m] (overwrites X) ----
    {
        const int SC = (nw + 63) >> 6;
        #pragma unroll 1
        for (int strip = 0; strip < SC; ++strip) {
            const int m = strip*64 + lane;          // local pooled-w row
            const int w = 2*r0 - 2 + m;
            const bool wok = (m < nw) && (w >= 0) && (w < 1025);
            float acc0[8], acc1[8];
            #pragma unroll
            for (int io = 0; io < 8; ++io) { acc0[io] = 0.f; acc1[io] = 0.f; }
            #pragma unroll 1
            for (int cb = 0; cb < 8; ++cb) {        // runtime: weight addr depends on cb
                #pragma unroll
                for (int cq = 0; cq < 2; ++cq) {
                    const int ci = cb*2 + cq;
                    const float* pw = sm + SM_P1 + ci*LUP + 2*m;
                    float p0 = pw[0], p1 = pw[1], p2v = pw[2], p3 = pw[3];
                    #pragma unroll
                    for (int io = 0; io < 8; ++io) {
                        const int ou = __builtin_amdgcn_readfirstlane(wid + 4*io);
                        const float* wp = w2 + ou*48 + ci*3;
                        float wv0 = wp[0], wv1 = wp[1], wv2 = wp[2];
                        acc0[io] = fmaf(p0,  wv0, acc0[io]);
                        acc1[io] = fmaf(p1,  wv0, acc1[io]);
                        acc0[io] = fmaf(p1,  wv1, acc0[io]);
                        acc1[io] = fmaf(p2v, wv1, acc1[io]);
                        acc0[io] = fmaf(p2v, wv2, acc0[io]);
                        acc1[io] = fmaf(p3,  wv2, acc1[io]);
                    }
                }
            }
            #pragma unroll
            for (int io = 0; io < 8; ++io) {
                const int ou = __builtin_amdgcn_readfirstlane(wid + 4*io);
                const float bo = b2[ou];
                float res = wok ? fmaxf(fmaxf(acc0[io] + bo, acc1[io] + bo), 0.f) : 0.f;
                if (m < nw) sm[SM_P2 + ou*LWP + m] = res;   // 0 = conv pad for stage D
            }
        }
    }
    __syncthreads();

    // ---- stage D: conv3(32->16,k3,p2)+relu+pool2 -> sum over r -> feat ----
    {
        const bool rok = (lane < nr);
        float acc0[4], acc1[4];
        #pragma unroll
        for (int io = 0; io < 4; ++io) { acc0[io] = 0.f; acc1[io] = 0.f; }
        #pragma unroll 1
        for (int cb = 0; cb < 8; ++cb) {            // runtime: weight addr depends on cb
            #pragma unroll
            for (int cq = 0; cq < 4; ++cq) {
                const int ci = cb*4 + cq;
                const float* pw = sm + SM_P2 + ci*LWP + 2*lane;
                float p0 = pw[0], p1 = pw[1], p2v = pw[2], p3 = pw[3];
                #pragma unroll
                for (int io = 0; io < 4; ++io) {
                    const int ou = __builtin_amdgcn_readfirstlane(wid + 4*io);
                    const float* wp = w3 + ou*96 + ci*3;
                    float wv0 = wp[0], wv1 = wp[1], wv2 = wp[2];
                    acc0[io] = fmaf(p0,  wv0, acc0[io]);
                    acc1[io] = fmaf(p1,  wv0, acc1[io]);
                    acc0[io] = fmaf(p1,  wv1, acc0[io]);
                    acc1[io] = fmaf(p2v, wv1, acc1[io]);
                    acc0[io] = fmaf(p2v, wv2, acc0[io]);
                    acc1[io] = fmaf(p3,  wv2, acc1[io]);
                }
            }
        }
        #pragma unroll
        for (int io = 0; io < 4; ++io) {
            const int ou = __builtin_amdgcn_readfirstlane(wid + 4*io);
            const float bo = b3[ou];
            float v = fmaxf(fmaxf(acc0[io] + bo, acc1[io] + bo), 0.f);
            v = rok ? v : 0.f;
            #pragma unroll
            for (int off = 32; off >= 1; off >>= 1)
                v += __shfl_down(v, off, 64);
            if (lane == 0) atomicAdd(&feat[n*16 + ou], v);
        }
    }
}

// feat [2048,16] viewed as [256,128]; out[b][q] = max(feat[b,3q..3q+2]) / 513
__global__ void finalize_kernel(const float* __restrict__ feat, float* __restrict__ out) {
    int i = blockIdx.x * blockDim.x + threadIdx.x;
    if (i < 256*42) {
        int b = i / 42;
        int q = i - b*42;
        const float* f = feat + b*128 + q*3;
        out[i] = fmaxf(fmaxf(f[0], f[1]), f[2]) * (1.0f/513.0f);
    }
}

extern "C" void kernel_launch(void* const* d_in, const int* in_sizes, int n_in,
                              void* d_out, int out_size, void* d_ws, size_t ws_size,
                              hipStream_t stream) {
    const float* x  = (const float*)d_in[0];
    const float* w1 = (const float*)d_in[1];
    const float* b1 = (const float*)d_in[2];
    const float* w2 = (const float*)d_in[3];
    const float* b2 = (const float*)d_in[4];
    const float* w3 = (const float*)d_in[5];
    const float* b3 = (const float*)d_in[6];
    float* feat = (float*)d_ws;                       // 2048*16 floats = 128 KB
    hipMemsetAsync(feat, 0, NS*16*sizeof(float), stream);
    dim3 grid(NCHUNK, NS);
    fused_cnn<<<grid, 256, 0, stream>>>(x, w1, b1, w2, b2, w3, b3, feat);
    finalize_kernel<<<(256*42 + 255)/256, 256, 0, stream>>>(feat, (float*)d_out);
}

// Round 5
// 782.492 us; speedup vs baseline: 1.4077x; 1.1277x over previous
//
#include <hip/hip_runtime.h>

#define NS 2048      // series = 256*8
#define T 4096
#define F 9
#define CH 62        // pooled-final rows per chunk -> nw=126 (2 clean strips)
#define NCHUNK 9     // 8*62=496, last chunk nr=17

typedef float v2f __attribute__((ext_vector_type(2)));

// LDS: channel-major, time-contiguous, even strides
#define LXP 514      // x:  [9][514]   rows t_local in [0,510)
#define LUP 258      // p1: [16][258]  rows j in [0,254)
#define LWP 130      // p2: [32][130]  rows m in [0,126)
#define SM_X  0                  // 9*514  = 4626 floats
#define SM_P2 0                  // 32*130 = 4160 floats (overlaps X; X dead by then)
#define SM_P1 4640               // 16*258 = 4128 floats
#define SM_TOT (4640 + 16*258)   // 8768 floats = 35072 B -> 4 blocks/CU

// Weight s_loads chunked behind `#pragma unroll 1` runtime loops (addr depends on
// loop var -> no LICM hoist -> no SGPR spill). Weight-block OUTER / strip INNER so
// weights load once per block-stage, not once per strip. Pooled pair (a0,a1) packed
// into v2f -> v_pk_fma_f32 halves FMA instruction count.
__global__ __launch_bounds__(256) __attribute__((amdgpu_waves_per_eu(4, 4)))
void fused_cnn(
    const float* __restrict__ x,
    const float* __restrict__ w1, const float* __restrict__ b1,
    const float* __restrict__ w2, const float* __restrict__ b2,
    const float* __restrict__ w3, const float* __restrict__ b3,
    float* __restrict__ feat)
{
    __shared__ float sm[SM_TOT];
    const int tid  = threadIdx.x;
    const int lane = tid & 63;
    const int wid  = tid >> 6;          // wave id 0..3
    const int chunk = blockIdx.x;
    const int n     = blockIdx.y;
    const int r0 = chunk * CH;
    const int nr = min(CH, 513 - r0);   // 62, or 17 on last chunk
    const int nw = 2*nr + 2;            // p2 rows
    const int nu = 4*nr + 6;            // p1 rows
    const int nx = 8*nr + 14;           // x rows

    // ---- stage A: x window -> LDS transposed [f][t_local], zero-padded ----
    {
        const float* xs = x + (size_t)n * (T*F);
        const int gbase = (8*r0 - 14) * F;   // = t0*9
        const int tot = nx * F;
        for (int i = tid; i < tot; i += 256) {
            int tl = i / 9;
            int f  = i - tl*9;
            int gi = gbase + i;
            float v = (gi >= 0 && gi < T*F) ? xs[gi] : 0.f;
            sm[SM_X + f*LXP + tl] = v;
        }
    }
    __syncthreads();

    // ---- stage B: conv1(9->16,k3,p2)+relu+pool2 -> p1[c][j] ----
    {
        v2f acc[4][4];
        #pragma unroll
        for (int s = 0; s < 4; ++s)
            #pragma unroll
            for (int ic = 0; ic < 4; ++ic) acc[s][ic] = (v2f){0.f, 0.f};
        #pragma unroll 1
        for (int fb = 0; fb < 3; ++fb) {          // weight addr depends on fb
            float wv[3][4][3];
            #pragma unroll
            for (int fi = 0; fi < 3; ++fi)
                #pragma unroll
                for (int ic = 0; ic < 4; ++ic) {
                    const int cu = __builtin_amdgcn_readfirstlane(wid + 4*ic);
                    const float* wp = w1 + cu*27 + (fb*3 + fi)*3;
                    wv[fi][ic][0] = wp[0]; wv[fi][ic][1] = wp[1]; wv[fi][ic][2] = wp[2];
                }
            #pragma unroll
            for (int s = 0; s < 4; ++s) {
                if (s*64 < nu) {
                    const int j = s*64 + lane;
                    #pragma unroll
                    for (int fi = 0; fi < 3; ++fi) {
                        const float* xw = sm + SM_X + (fb*3 + fi)*LXP + 2*j;
                        float x0 = xw[0], x1 = xw[1], x2 = xw[2], x3 = xw[3];
                        v2f p01 = {x0, x1}, p12 = {x1, x2}, p23 = {x2, x3};
                        #pragma unroll
                        for (int ic = 0; ic < 4; ++ic) {
                            v2f w0s = {wv[fi][ic][0], wv[fi][ic][0]};
                            v2f w1s = {wv[fi][ic][1], wv[fi][ic][1]};
                            v2f w2s = {wv[fi][ic][2], wv[fi][ic][2]};
                            acc[s][ic] = __builtin_elementwise_fma(p01, w0s, acc[s][ic]);
                            acc[s][ic] = __builtin_elementwise_fma(p12, w1s, acc[s][ic]);
                            acc[s][ic] = __builtin_elementwise_fma(p23, w2s, acc[s][ic]);
                        }
                    }
                }
            }
        }
        #pragma unroll
        for (int s = 0; s < 4; ++s) {
            if (s*64 < nu) {
                const int j = s*64 + lane;
                const int u = 4*r0 - 6 + j;
                const bool uok = (j < nu) && (u >= 0) && (u < 2049);
                #pragma unroll
                for (int ic = 0; ic < 4; ++ic) {
                    const int cu = __builtin_amdgcn_readfirstlane(wid + 4*ic);
                    const float bc = b1[cu];
                    float res = uok ? fmaxf(fmaxf(acc[s][ic].x + bc, acc[s][ic].y + bc), 0.f) : 0.f;
                    if (j < nu) sm[SM_P1 + cu*LUP + j] = res;   // 0 = conv pad for stage C
                }
            }
        }
    }
    __syncthreads();

    // ---- stage C: conv2(16->32,k3,p2)+relu+pool2 -> p2[o][m] (overwrites X) ----
    {
        v2f acc[2][8];
        #pragma unroll
        for (int s = 0; s < 2; ++s)
            #pragma unroll
            for (int io = 0; io < 8; ++io) acc[s][io] = (v2f){0.f, 0.f};
        #pragma unroll 1
        for (int cb = 0; cb < 8; ++cb) {          // weight addr depends on cb
            float wv[2][8][3];
            #pragma unroll
            for (int cq = 0; cq < 2; ++cq)
                #pragma unroll
                for (int io = 0; io < 8; ++io) {
                    const int ou = __builtin_amdgcn_readfirstlane(wid + 4*io);
                    const float* wp = w2 + ou*48 + (cb*2 + cq)*3;
                    wv[cq][io][0] = wp[0]; wv[cq][io][1] = wp[1]; wv[cq][io][2] = wp[2];
                }
            #pragma unroll
            for (int s = 0; s < 2; ++s) {
                if (s*64 < nw) {
                    const int m = s*64 + lane;
                    #pragma unroll
                    for (int cq = 0; cq < 2; ++cq) {
                        const float* pw = sm + SM_P1 + (cb*2 + cq)*LUP + 2*m;
                        float p0 = pw[0], p1 = pw[1], p2v = pw[2], p3 = pw[3];
                        v2f q01 = {p0, p1}, q12 = {p1, p2v}, q23 = {p2v, p3};
                        #pragma unroll
                        for (int io = 0; io < 8; ++io) {
                            v2f w0s = {wv[cq][io][0], wv[cq][io][0]};
                            v2f w1s = {wv[cq][io][1], wv[cq][io][1]};
                            v2f w2s = {wv[cq][io][2], wv[cq][io][2]};
                            acc[s][io] = __builtin_elementwise_fma(q01, w0s, acc[s][io]);
                            acc[s][io] = __builtin_elementwise_fma(q12, w1s, acc[s][io]);
                            acc[s][io] = __builtin_elementwise_fma(q23, w2s, acc[s][io]);
                        }
                    }
                }
            }
        }
        __syncthreads();   // X region still being read? no — X dead since stage B. P2 overwrites X; ensure all waves done reading... X dead, but P2 aliases X which stage B read. Stage B ended at previous barrier. Safe to store now.
        #pragma unroll
        for (int s = 0; s < 2; ++s) {
            if (s*64 < nw) {
                const int m = s*64 + lane;
                const int w = 2*r0 - 2 + m;
                const bool wok = (m < nw) && (w >= 0) && (w < 1025);
                #pragma unroll
                for (int io = 0; io < 8; ++io) {
                    const int ou = __builtin_amdgcn_readfirstlane(wid + 4*io);
                    const float bo = b2[ou];
                    float res = wok ? fmaxf(fmaxf(acc[s][io].x + bo, acc[s][io].y + bo), 0.f) : 0.f;
                    if (m < nw) sm[SM_P2 + ou*LWP + m] = res;   // 0 = conv pad for stage D
                }
            }
        }
    }
    __syncthreads();

    // ---- stage D: conv3(32->16,k3,p2)+relu+pool2 -> sum over r -> feat ----
    {
        const bool rok = (lane < nr);
        v2f acc[4];
        #pragma unroll
        for (int io = 0; io < 4; ++io) acc[io] = (v2f){0.f, 0.f};
        #pragma unroll 1
        for (int cb = 0; cb < 8; ++cb) {          // weight addr depends on cb
            float wv[4][4][3];
            #pragma unroll
            for (int cq = 0; cq < 4; ++cq)
                #pragma unroll
                for (int io = 0; io < 4; ++io) {
                    const int ou = __builtin_amdgcn_readfirstlane(wid + 4*io);
                    const float* wp = w3 + ou*96 + (cb*4 + cq)*3;
                    wv[cq][io][0] = wp[0]; wv[cq][io][1] = wp[1]; wv[cq][io][2] = wp[2];
                }
            #pragma unroll
            for (int cq = 0; cq < 4; ++cq) {
                const float* pw = sm + SM_P2 + (cb*4 + cq)*LWP + 2*lane;
                float p0 = pw[0], p1 = pw[1], p2v = pw[2], p3 = pw[3];
                v2f q01 = {p0, p1}, q12 = {p1, p2v}, q23 = {p2v, p3};
                #pragma unroll
                for (int io = 0; io < 4; ++io) {
                    v2f w0s = {wv[cq][io][0], wv[cq][io][0]};
                    v2f w1s = {wv[cq][io][1], wv[cq][io][1]};
                    v2f w2s = {wv[cq][io][2], wv[cq][io][2]};
                    acc[io] = __builtin_elementwise_fma(q01, w0s, acc[io]);
                    acc[io] = __builtin_elementwise_fma(q12, w1s, acc[io]);
                    acc[io] = __builtin_elementwise_fma(q23, w2s, acc[io]);
                }
            }
        }
        #pragma unroll
        for (int io = 0; io < 4; ++io) {
            const int ou = __builtin_amdgcn_readfirstlane(wid + 4*io);
            const float bo = b3[ou];
            float v = fmaxf(fmaxf(acc[io].x + bo, acc[io].y + bo), 0.f);
            v = rok ? v : 0.f;
            #pragma unroll
            for (int off = 32; off >= 1; off >>= 1)
                v += __shfl_down(v, off, 64);
            if (lane == 0) atomicAdd(&feat[n*16 + ou], v);
        }
    }
}

// feat [2048,16] viewed as [256,128]; out[b][q] = max(feat[b,3q..3q+2]) / 513
__global__ void finalize_kernel(const float* __restrict__ feat, float* __restrict__ out) {
    int i = blockIdx.x * blockDim.x + threadIdx.x;
    if (i < 256*42) {
        int b = i / 42;
        int q = i - b*42;
        const float* f = feat + b*128 + q*3;
        out[i] = fmaxf(fmaxf(f[0], f[1]), f[2]) * (1.0f/513.0f);
    }
}

extern "C" void kernel_launch(void* const* d_in, const int* in_sizes, int n_in,
                              void* d_out, int out_size, void* d_ws, size_t ws_size,
                              hipStream_t stream) {
    const float* x  = (const float*)d_in[0];
    const float* w1 = (const float*)d_in[1];
    const float* b1 = (const float*)d_in[2];
    const float* w2 = (const float*)d_in[3];
    const float* b2 = (const float*)d_in[4];
    const float* w3 = (const float*)d_in[5];
    const float* b3 = (const float*)d_in[6];
    float* feat = (float*)d_ws;                       // 2048*16 floats = 128 KB
    hipMemsetAsync(feat, 0, NS*16*sizeof(float), stream);
    dim3 grid(NCHUNK, NS);
    fused_cnn<<<grid, 256, 0, stream>>>(x, w1, b1, w2, b2, w3, b3, feat);
    finalize_kernel<<<(256*42 + 255)/256, 256, 0, stream>>>(feat, (float*)d_out);
}